// Round 5
// baseline (1353.148 us; speedup 1.0000x reference)
//
#include <hip/hip_runtime.h>
#include <hip/hip_cooperative_groups.h>

namespace cg = cooperative_groups;

#define B_ 8
#define V_ 2048
#define D_ 3
#define M_ (B_*V_)   // 16384 rows

typedef __attribute__((ext_vector_type(8))) short short8;
typedef __attribute__((ext_vector_type(4))) float f32x4;

__device__ inline void async_copy16(const void* g, void* lds) {
  __builtin_amdgcn_global_load_lds(
      (const __attribute__((address_space(1))) unsigned int*)g,
      (__attribute__((address_space(3))) unsigned int*)lds, 16, 0, 0);
}

__device__ inline void split_bf16(float v, short& hi, short& lo) {
  unsigned u  = __float_as_uint(v);
  unsigned hb = u & 0xFFFF0000u;
  float d = v - __uint_as_float(hb);
  hi = (short)(hb >> 16);
  lo = (short)(__float_as_uint(d) >> 16);
}

// ---------------------------------------------------------------------------
// k_prep: materialize XK (slot 0 from x-transpose, pads zero) + xa transpose
// + split all 4 weight matrices.  One launch, 5040 blocks x 256.
// ---------------------------------------------------------------------------
__global__ __launch_bounds__(256) void k_prep(
    const float* __restrict__ x,
    const float* __restrict__ w1, const float* __restrict__ w2,
    const float* __restrict__ fw1, const float* __restrict__ fw2,
    float* __restrict__ xa,
    short* __restrict__ XKh, short* __restrict__ XKl,
    short* __restrict__ w1h, short* __restrict__ w1l,
    short* __restrict__ w2h, short* __restrict__ w2l,
    short* __restrict__ fw1h, short* __restrict__ fw1l,
    short* __restrict__ fw2h, short* __restrict__ fw2l) {
  int i = blockIdx.x * 256 + threadIdx.x;
  short hi, lo;
  if (i < M_*64) {   // XK: row r = i>>6, slot s = i&63; slot = f*6+k, k=0 live
    int r = i >> 6, s = i & 63;
    float val = 0.f;
    if (s == 0 || s == 6 || s == 12) {
      int f = s / 6;
      int b = r >> 11, v = r & (V_-1);
      val = x[((size_t)b*D_ + f)*V_ + v];
      xa[(size_t)r*3 + f] = val;
    }
    split_bf16(val, hi, lo);
    XKh[i] = hi; XKl[i] = lo;
    return;
  }
  i -= M_*64;
  if (i < 4096) {          // w1: [64,18] -> [64,64] padded
    int n = i >> 6, k = i & 63;
    float v = (k < 18) ? w1[n*18 + k] : 0.f;
    split_bf16(v, hi, lo); w1h[i] = hi; w1l[i] = lo; return;
  }
  i -= 4096;
  if (i < 40960) { split_bf16(w2[i],  hi, lo); w2h[i]=hi;  w2l[i]=lo;  return; }
  i -= 40960;
  if (i < 65536) { split_bf16(fw1[i], hi, lo); fw1h[i]=hi; fw1l[i]=lo; return; }
  i -= 65536;
  if (i < 131072){ split_bf16(fw2[i], hi, lo); fw2h[i]=hi; fw2l[i]=lo; return; }
}

// ---------------------------------------------------------------------------
// k_cheby1_all (cooperative): 5 cheby1 steps, grid.sync between steps.
// 512 blocks x 256 (2 blocks/CU guaranteed).  LDS 24 KB.
// ---------------------------------------------------------------------------
__global__ __launch_bounds__(256, 2) void k_cheby1_all(
    const float* __restrict__ L, float* __restrict__ xa,
    float* __restrict__ xb, float* __restrict__ xc,
    short* __restrict__ XKh, short* __restrict__ XKl) {
  cg::grid_group grid = cg::this_grid();
  __shared__ float sx[3][V_];  // 24 KB

  const float* srcs[5]  = {xa, xb, xc, xa, xb};
  const float* prevs[5] = {xa, xa, xb, xc, xa};
  float*       dsts[5]  = {xb, xc, xa, xb, xc};

  int b  = blockIdx.x >> 6;
  int r0 = (blockIdx.x & 63) * 32;
  int w = threadIdx.x >> 6, lane = threadIdx.x & 63;

  for (int step = 0; step < 5; step++) {
    float alpha = (step == 0) ? 1.f : 2.f;
    bool  haveP = (step != 0);
    const float* xcb = srcs[step] + (size_t)b*V_*D_;
    const float* xp  = prevs[step];
    float* xn = dsts[step];
    int kidx = step + 1;

    for (int i = threadIdx.x; i < V_*D_; i += 256) {
      int u = i / 3, f = i - u*3;
      sx[f][u] = xcb[i];
    }
    __syncthreads();

    const float4* X0 = (const float4*)sx[0];
    const float4* X1 = (const float4*)sx[1];
    const float4* X2 = (const float4*)sx[2];
    for (int pass = 0; pass < 4; pass++) {
      int rA = r0 + pass*8 + w*2;
      int rB = rA + 1;
      const float4* LA = (const float4*)(L + ((size_t)b*V_ + rA)*V_);
      const float4* LB = (const float4*)(L + ((size_t)b*V_ + rB)*V_);
      float a0=0.f,a1=0.f,a2=0.f,b0=0.f,b1=0.f,b2=0.f;
      #pragma unroll
      for (int it = 0; it < 8; it++) {
        int u4 = it*64 + lane;
        float4 la = LA[u4], lb = LB[u4];
        float4 x0 = X0[u4], x1 = X1[u4], x2 = X2[u4];
        a0 = fmaf(la.x,x0.x,fmaf(la.y,x0.y,fmaf(la.z,x0.z,fmaf(la.w,x0.w,a0))));
        a1 = fmaf(la.x,x1.x,fmaf(la.y,x1.y,fmaf(la.z,x1.z,fmaf(la.w,x1.w,a1))));
        a2 = fmaf(la.x,x2.x,fmaf(la.y,x2.y,fmaf(la.z,x2.z,fmaf(la.w,x2.w,a2))));
        b0 = fmaf(lb.x,x0.x,fmaf(lb.y,x0.y,fmaf(lb.z,x0.z,fmaf(lb.w,x0.w,b0))));
        b1 = fmaf(lb.x,x1.x,fmaf(lb.y,x1.y,fmaf(lb.z,x1.z,fmaf(lb.w,x1.w,b1))));
        b2 = fmaf(lb.x,x2.x,fmaf(lb.y,x2.y,fmaf(lb.z,x2.z,fmaf(lb.w,x2.w,b2))));
      }
      #pragma unroll
      for (int off = 32; off > 0; off >>= 1) {
        a0 += __shfl_down(a0, off); a1 += __shfl_down(a1, off);
        a2 += __shfl_down(a2, off); b0 += __shfl_down(b0, off);
        b1 += __shfl_down(b1, off); b2 += __shfl_down(b2, off);
      }
      if (lane == 0) {
        float vA[3] = {alpha*a0, alpha*a1, alpha*a2};
        float vB[3] = {alpha*b0, alpha*b1, alpha*b2};
        size_t baseA = ((size_t)b*V_ + rA)*3;
        size_t baseB = ((size_t)b*V_ + rB)*3;
        if (haveP) {
          #pragma unroll
          for (int f = 0; f < 3; f++) {
            vA[f] -= xp[baseA + f];
            vB[f] -= xp[baseB + f];
          }
        }
        #pragma unroll
        for (int f = 0; f < 3; f++) {
          xn[baseA + f] = vA[f];
          xn[baseB + f] = vB[f];
          short hi, lo;
          split_bf16(vA[f], hi, lo);
          size_t oA = ((size_t)b*V_ + rA)*64 + f*6 + kidx;
          XKh[oA] = hi; XKl[oA] = lo;
          split_bf16(vB[f], hi, lo);
          size_t oB = ((size_t)b*V_ + rB)*64 + f*6 + kidx;
          XKh[oB] = hi; XKl[oB] = lo;
        }
      }
    }
    grid.sync();
  }
}

// ---------------------------------------------------------------------------
// gemm_tile: one 64x64 output tile of C = relu(A[M,K] @ W[N,K]^T + bias),
// split-bf16 MFMA.  A/W pre-split hi/lo bf16, K mult of 64.
// ---------------------------------------------------------------------------
__device__ __forceinline__ void gemm_tile(
    const short* __restrict__ Ah, const short* __restrict__ Al,
    const short* __restrict__ Wh, const short* __restrict__ Wl,
    const float* __restrict__ bias, int N, int K, int row0, int col0,
    short* sAh, short* sAl, short* sWh, short* sWl,
    float* __restrict__ Cf, short* __restrict__ Ch, short* __restrict__ Cl,
    short* __restrict__ Ph, short* __restrict__ Pl, int packMul, int packStride,
    short* __restrict__ Th, short* __restrict__ Tl) {
  int tid = threadIdx.x, w = tid >> 6, lane = tid & 63;
  int lm = lane & 15, quad = lane >> 4;
  int wm = (w & 1) * 32, wn = (w >> 1) * 32;

  const short8* vAh = (const short8*)sAh;
  const short8* vAl = (const short8*)sAl;
  const short8* vWh = (const short8*)sWh;
  const short8* vWl = (const short8*)sWl;

  f32x4 acc[2][2] = {{{0.f,0.f,0.f,0.f},{0.f,0.f,0.f,0.f}},
                     {{0.f,0.f,0.f,0.f},{0.f,0.f,0.f,0.f}}};

  for (int k0 = 0; k0 < K; k0 += 64) {
    __syncthreads();
    #pragma unroll
    for (int t = 0; t < 2; t++) {
      int f = t*256 + tid;
      int r = f >> 3, p = f & 7;
      int c = p ^ (r & 7);
      size_t goA = (size_t)(row0 + r)*K + k0 + c*8;
      size_t goW = (size_t)(col0 + r)*K + k0 + c*8;
      async_copy16(Ah + goA, &sAh[f*8]);
      async_copy16(Al + goA, &sAl[f*8]);
      async_copy16(Wh + goW, &sWh[f*8]);
      async_copy16(Wl + goW, &sWl[f*8]);
    }
    __syncthreads();

    #pragma unroll
    for (int ks = 0; ks < 2; ks++) {
      int kc = ks*4 + quad;
      short8 a_h[2], a_l[2], b_h[2], b_l[2];
      #pragma unroll
      for (int i = 0; i < 2; i++) {
        int m = wm + i*16 + lm;
        a_h[i] = vAh[m*8 + (kc ^ (m & 7))];
        a_l[i] = vAl[m*8 + (kc ^ (m & 7))];
      }
      #pragma unroll
      for (int j = 0; j < 2; j++) {
        int n = wn + j*16 + lm;
        b_h[j] = vWh[n*8 + (kc ^ (n & 7))];
        b_l[j] = vWl[n*8 + (kc ^ (n & 7))];
      }
      #pragma unroll
      for (int i = 0; i < 2; i++)
        #pragma unroll
        for (int j = 0; j < 2; j++) {
          acc[i][j] = __builtin_amdgcn_mfma_f32_16x16x32_bf16(a_h[i], b_h[j], acc[i][j], 0, 0, 0);
          acc[i][j] = __builtin_amdgcn_mfma_f32_16x16x32_bf16(a_h[i], b_l[j], acc[i][j], 0, 0, 0);
          acc[i][j] = __builtin_amdgcn_mfma_f32_16x16x32_bf16(a_l[i], b_h[j], acc[i][j], 0, 0, 0);
        }
    }
  }

  #pragma unroll
  for (int i = 0; i < 2; i++)
    #pragma unroll
    for (int j = 0; j < 2; j++) {
      int col = col0 + wn + j*16 + lm;
      float bj = bias[col];
      #pragma unroll
      for (int g = 0; g < 4; g++) {
        int row = row0 + wm + i*16 + quad*4 + g;
        float v = acc[i][j][g] + bj;
        v = v > 0.f ? v : 0.f;
        if (Cf) Cf[(size_t)row*N + col] = v;
        short hi, lo;
        if (Ch || Ph || Th) split_bf16(v, hi, lo);
        if (Ch) {
          Ch[(size_t)row*N + col] = hi;
          Cl[(size_t)row*N + col] = lo;
        }
        if (Ph) {
          size_t o = (size_t)row*packStride + (size_t)col*packMul;
          Ph[o] = hi; Pl[o] = lo;
        }
        if (Th) {  // transposed [B,64,V] (N==64)
          int bb = row >> 11, vv = row & (V_-1);
          size_t o = ((size_t)bb*64 + col)*V_ + vv;
          Th[o] = hi; Tl[o] = lo;
        }
      }
    }
}

// ---------------------------------------------------------------------------
// k_gemm_y1: y1 = relu(XK @ w1^T + b1); writes y1 fp32, ZK pack slot 0,
// and ZtA hi/lo transposed.  256 blocks (N=64), regular launch.
// ---------------------------------------------------------------------------
__global__ __launch_bounds__(256) void k_gemm_y1(
    const short* __restrict__ XKh, const short* __restrict__ XKl,
    const short* __restrict__ w1h, const short* __restrict__ w1l,
    const float* __restrict__ b1, float* __restrict__ y1,
    short* __restrict__ ZKh, short* __restrict__ ZKl,
    short* __restrict__ Th, short* __restrict__ Tl) {
  __shared__ short sAh[64*64], sAl[64*64], sWh[64*64], sWl[64*64];
  gemm_tile(XKh, XKl, w1h, w1l, b1, 64, 64, blockIdx.x*64, 0,
            sAh, sAl, sWh, sWl,
            y1, nullptr, nullptr, ZKh, ZKl, 5, 320, Th, Tl);
}

// ---------------------------------------------------------------------------
// k_cheby2_all (cooperative): 4 cheby2 MFMA steps with grid.sync.
// 512 blocks x 256 (2 blocks/CU), LDS 24 KB.
// ---------------------------------------------------------------------------
__global__ __launch_bounds__(256, 2) void k_cheby2_all(const float* __restrict__ L,
    short* __restrict__ ZtAh, short* __restrict__ ZtAl,
    short* __restrict__ ZtBh, short* __restrict__ ZtBl,
    float* __restrict__ y1, float* __restrict__ zb, float* __restrict__ zc,
    short* __restrict__ ZKh, short* __restrict__ ZKl) {
  cg::grid_group grid = cg::this_grid();
  __shared__ float sA[32*64];
  __shared__ short sBh[64*64];
  __shared__ short sBl[64*64];

  int b  = blockIdx.x >> 6;
  int r0 = (blockIdx.x & 63) * 32;
  const float* Lb = L + (size_t)b*V_*V_;

  int tid = threadIdx.x, w = tid >> 6, lane = tid & 63;
  int lm = lane & 15, quad = lane >> 4;
  int h = (w & 1) * 16, cbase = (w >> 1) * 32;

  const f32x4*  sAv  = (const f32x4*)sA;
  const short8* sBhv = (const short8*)sBh;
  const short8* sBlv = (const short8*)sBl;

  const short* Bh[4] = {ZtAh, ZtBh, ZtAh, ZtBh};
  const short* Bl[4] = {ZtAl, ZtBl, ZtAl, ZtBl};
  short* Thh[4] = {ZtBh, ZtAh, ZtBh, ZtAh};
  short* Tll[4] = {ZtBl, ZtAl, ZtBl, ZtAl};
  const float* Zp[4] = {nullptr, y1, zb, zc};
  float* Zd[4] = {zb, zc, y1, zb};

  for (int step = 0; step < 4; step++) {
    float alpha = (step == 0) ? 1.f : 2.f;
    const short* Zthb = Bh[step] + (size_t)b*64*V_;
    const short* Ztlb = Bl[step] + (size_t)b*64*V_;
    f32x4 acc0 = {0.f,0.f,0.f,0.f};
    f32x4 acc1 = {0.f,0.f,0.f,0.f};

    for (int s = 0; s < V_/64; s++) {
      int k0 = s * 64;
      if (s) __syncthreads();
      #pragma unroll
      for (int t = 0; t < 2; t++) {
        int f = t*256 + tid;
        int r = f >> 4, cc = f & 15;
        int c = cc ^ (r & 15);
        async_copy16(Lb + (size_t)(r0 + r)*V_ + k0 + c*4, &sA[f*4]);
      }
      #pragma unroll
      for (int t = 0; t < 2; t++) {
        int f = t*256 + tid;
        int n = f >> 3, cc = f & 7;
        int c = cc ^ (n & 7);
        async_copy16(Zthb + (size_t)n*V_ + k0 + c*8, &sBh[f*8]);
        async_copy16(Ztlb + (size_t)n*V_ + k0 + c*8, &sBl[f*8]);
      }
      __syncthreads();

      #pragma unroll
      for (int ks = 0; ks < 2; ks++) {
        int koff = ks * 32;
        int r = h + lm;
        int c0 = (koff >> 2) + 2*quad;
        f32x4 a0 = sAv[r*16 + (c0 ^ (r & 15))];
        f32x4 a1 = sAv[r*16 + ((c0 + 1) ^ (r & 15))];
        float av[8] = {a0.x, a0.y, a0.z, a0.w, a1.x, a1.y, a1.z, a1.w};
        short8 ah, al;
        #pragma unroll
        for (int j = 0; j < 8; j++) {
          short hi, lo; split_bf16(av[j], hi, lo);
          ah[j] = hi; al[j] = lo;
        }
        int cb = (koff >> 3) + quad;
        {
          int n = cbase + lm;
          short8 bh = sBhv[n*8 + (cb ^ (n & 7))];
          short8 bl = sBlv[n*8 + (cb ^ (n & 7))];
          acc0 = __builtin_amdgcn_mfma_f32_16x16x32_bf16(ah, bh, acc0, 0, 0, 0);
          acc0 = __builtin_amdgcn_mfma_f32_16x16x32_bf16(ah, bl, acc0, 0, 0, 0);
          acc0 = __builtin_amdgcn_mfma_f32_16x16x32_bf16(al, bh, acc0, 0, 0, 0);
        }
        {
          int n = cbase + 16 + lm;
          short8 bh = sBhv[n*8 + (cb ^ (n & 7))];
          short8 bl = sBlv[n*8 + (cb ^ (n & 7))];
          acc1 = __builtin_amdgcn_mfma_f32_16x16x32_bf16(ah, bh, acc1, 0, 0, 0);
          acc1 = __builtin_amdgcn_mfma_f32_16x16x32_bf16(ah, bl, acc1, 0, 0, 0);
          acc1 = __builtin_amdgcn_mfma_f32_16x16x32_bf16(al, bh, acc1, 0, 0, 0);
        }
      }
    }

    const float* zp = Zp[step];
    float* zn = Zd[step];
    short* Tho = Thh[step];
    short* Tlo = Tll[step];
    #pragma unroll
    for (int ct = 0; ct < 2; ct++) {
      f32x4 a = ct ? acc1 : acc0;
      int n = cbase + ct*16 + lm;
      #pragma unroll
      for (int i = 0; i < 4; i++) {
        int r = r0 + h + quad*4 + i;
        size_t rowb = (size_t)b*V_ + r;
        float v = alpha * a[i];
        if (zp) v -= zp[rowb*64 + n];
        zn[rowb*64 + n] = v;
        short hi, lo; split_bf16(v, hi, lo);
        size_t ok = rowb*320 + (size_t)n*5 + (step + 1);
        ZKh[ok] = hi; ZKl[ok] = lo;
        size_t o = ((size_t)b*64 + n)*V_ + r;
        Tho[o] = hi; Tlo[o] = lo;
      }
    }
    grid.sync();
  }
}

// ---------------------------------------------------------------------------
// k_fc_chain (cooperative, persistent): y2 -> h1 -> out, grid.sync between
// layers.  512 blocks x 256 (2 blocks/CU guaranteed), LDS 32 KB.
// ---------------------------------------------------------------------------
__global__ __launch_bounds__(256, 2) void k_fc_chain(
    const short* __restrict__ ZKh, const short* __restrict__ ZKl,
    const short* __restrict__ w2h, const short* __restrict__ w2l,
    const float* __restrict__ b2,
    short* __restrict__ y2h, short* __restrict__ y2l,
    const short* __restrict__ fw1h, const short* __restrict__ fw1l,
    const float* __restrict__ fb1,
    short* __restrict__ h1h, short* __restrict__ h1l,
    const short* __restrict__ fw2h, const short* __restrict__ fw2l,
    const float* __restrict__ fb2,
    float* __restrict__ out) {
  cg::grid_group grid = cg::this_grid();
  __shared__ short sAh[64*64], sAl[64*64], sWh[64*64], sWl[64*64];

  // layer 1: [M,320] @ [128,320]^T -> y2 bf16 hi/lo.  512 tiles.
  for (int t = blockIdx.x; t < 512; t += 512) {
    int bm = t & 255, bn = t >> 8;
    gemm_tile(ZKh, ZKl, w2h, w2l, b2, 128, 320, bm*64, bn*64,
              sAh, sAl, sWh, sWl,
              nullptr, y2h, y2l, nullptr, nullptr, 0, 0, nullptr, nullptr);
  }
  grid.sync();
  // layer 2: [M,128] @ [512,128]^T -> h1 bf16 hi/lo.  2048 tiles.
  for (int t = blockIdx.x; t < 2048; t += 512) {
    int bm = t & 255, bn = t >> 8;
    gemm_tile(y2h, y2l, fw1h, fw1l, fb1, 512, 128, bm*64, bn*64,
              sAh, sAl, sWh, sWl,
              nullptr, h1h, h1l, nullptr, nullptr, 0, 0, nullptr, nullptr);
  }
  grid.sync();
  // layer 3: [M,512] @ [256,512]^T -> out fp32.  1024 tiles.
  for (int t = blockIdx.x; t < 1024; t += 512) {
    int bm = t & 255, bn = t >> 8;
    gemm_tile(h1h, h1l, fw2h, fw2l, fb2, 256, 512, bm*64, bn*64,
              sAh, sAl, sWh, sWl,
              out, nullptr, nullptr, nullptr, nullptr, 0, 0, nullptr, nullptr);
  }
}

// ---------------------------------------------------------------------------
extern "C" void kernel_launch(void* const* d_in, const int* in_sizes, int n_in,
                              void* d_out, int out_size, void* d_ws, size_t ws_size,
                              hipStream_t stream) {
  const float* x   = (const float*)d_in[0];
  const float* L   = (const float*)d_in[1];
  const float* w1  = (const float*)d_in[2];
  const float* b1  = (const float*)d_in[3];
  const float* w2  = (const float*)d_in[4];
  const float* b2  = (const float*)d_in[5];
  const float* fw1 = (const float*)d_in[6];
  const float* fb1 = (const float*)d_in[7];
  const float* fw2 = (const float*)d_in[8];
  const float* fb2 = (const float*)d_in[9];
  float* out = (float*)d_out;

  float* p  = (float*)d_ws;
  float* xa = p;  p += (size_t)B_*V_*D_;
  float* xb = p;  p += (size_t)B_*V_*D_;
  float* xc = p;  p += (size_t)B_*V_*D_;
  float* y1 = p;  p += (size_t)M_*64;
  float* zb = p;  p += (size_t)M_*64;
  float* zc = p;  p += (size_t)M_*64;
  short* sp = (short*)p;
  short* ZKh = sp;  sp += (size_t)M_*320;
  short* ZKl = sp;  sp += (size_t)M_*320;
  short* y2h = sp;  sp += (size_t)M_*128;
  short* y2l = sp;  sp += (size_t)M_*128;
  short* h1h = sp;  sp += (size_t)M_*512;
  short* h1l = sp;  sp += (size_t)M_*512;
  short* ZtAh = sp; sp += (size_t)M_*64;
  short* ZtAl = sp; sp += (size_t)M_*64;
  short* ZtBh = sp; sp += (size_t)M_*64;
  short* ZtBl = sp; sp += (size_t)M_*64;
  short* w1h = sp;  sp += 64*64;
  short* w1l = sp;  sp += 64*64;
  short* w2h = sp;  sp += 128*320;
  short* w2l = sp;  sp += 128*320;
  short* fw1h = sp; sp += 512*128;
  short* fw1l = sp; sp += 512*128;
  short* fw2h = sp; sp += 256*512;
  short* fw2l = sp; sp += 256*512;
  // XK aliased into h1h region (disjoint lifetimes: XK dead before h1 written)
  short* XKh = h1h;
  short* XKl = h1h + (size_t)M_*64;

  // 1) prep: XK (slot0 + zero pads) + xa transpose + weight splits
  k_prep<<<5040, 256, 0, stream>>>(x, w1, w2, fw1, fw2, xa,
                                   XKh, XKl, w1h, w1l, w2h, w2l,
                                   fw1h, fw1l, fw2h, fw2l);

  // 2) cheby1 (cooperative, 5 steps fused, 512 blocks = 2/CU)
  {
    void* a[] = {(void*)&L, (void*)&xa, (void*)&xb, (void*)&xc,
                 (void*)&XKh, (void*)&XKl};
    hipLaunchCooperativeKernel((void*)k_cheby1_all, dim3(512), dim3(256),
                               a, 0, stream);
  }

  // 3) y1-GEMM (+ ZK slot 0 pack + ZtA transposed split)
  k_gemm_y1<<<256, 256, 0, stream>>>(XKh, XKl, w1h, w1l, b1,
                                     y1, ZKh, ZKl, ZtAh, ZtAl);

  // 4) cheby2 (cooperative, 4 MFMA steps fused, 512 blocks = 2/CU)
  {
    void* a[] = {(void*)&L, (void*)&ZtAh, (void*)&ZtAl, (void*)&ZtBh,
                 (void*)&ZtBl, (void*)&y1, (void*)&zb, (void*)&zc,
                 (void*)&ZKh, (void*)&ZKl};
    hipLaunchCooperativeKernel((void*)k_cheby2_all, dim3(512), dim3(256),
                               a, 0, stream);
  }

  // 5) FC chain (cooperative persistent, 512 blocks = 2/CU)
  {
    void* a[] = {(void*)&ZKh, (void*)&ZKl, (void*)&w2h, (void*)&w2l,
                 (void*)&b2, (void*)&y2h, (void*)&y2l,
                 (void*)&fw1h, (void*)&fw1l, (void*)&fb1,
                 (void*)&h1h, (void*)&h1l,
                 (void*)&fw2h, (void*)&fw2l, (void*)&fb2, (void*)&out};
    hipLaunchCooperativeKernel((void*)k_fc_chain, dim3(512), dim3(256),
                               a, 0, stream);
  }
}

// Round 6
// 540.061 us; speedup vs baseline: 2.5055x; 2.5055x over previous
//
#include <hip/hip_runtime.h>

#define B_ 8
#define V_ 2048
#define D_ 3
#define M_ (B_*V_)   // 16384 rows

typedef __attribute__((ext_vector_type(8))) short short8;
typedef __attribute__((ext_vector_type(4))) float f32x4;

__device__ inline void async_copy16(const void* g, void* lds) {
  __builtin_amdgcn_global_load_lds(
      (const __attribute__((address_space(1))) unsigned int*)g,
      (__attribute__((address_space(3))) unsigned int*)lds, 16, 0, 0);
}

__device__ inline void split_bf16(float v, short& hi, short& lo) {
  unsigned u  = __float_as_uint(v);
  unsigned hb = u & 0xFFFF0000u;
  float d = v - __uint_as_float(hb);
  hi = (short)(hb >> 16);
  lo = (short)(__float_as_uint(d) >> 16);
}

// ---------------------------------------------------------------------------
// k_prep: materialize XK (slot 0 from x-transpose, pads zero) + xa transpose
// + split all 4 weight matrices.  One launch, 5040 blocks x 256.
// ---------------------------------------------------------------------------
__global__ __launch_bounds__(256) void k_prep(
    const float* __restrict__ x,
    const float* __restrict__ w1, const float* __restrict__ w2,
    const float* __restrict__ fw1, const float* __restrict__ fw2,
    float* __restrict__ xa,
    short* __restrict__ XKh, short* __restrict__ XKl,
    short* __restrict__ w1h, short* __restrict__ w1l,
    short* __restrict__ w2h, short* __restrict__ w2l,
    short* __restrict__ fw1h, short* __restrict__ fw1l,
    short* __restrict__ fw2h, short* __restrict__ fw2l) {
  int i = blockIdx.x * 256 + threadIdx.x;
  short hi, lo;
  if (i < M_*64) {   // XK: row r = i>>6, slot s = i&63; slot = f*6+k, k=0 live
    int r = i >> 6, s = i & 63;
    float val = 0.f;
    if (s == 0 || s == 6 || s == 12) {
      int f = s / 6;
      int b = r >> 11, v = r & (V_-1);
      val = x[((size_t)b*D_ + f)*V_ + v];
      xa[(size_t)r*3 + f] = val;
    }
    split_bf16(val, hi, lo);
    XKh[i] = hi; XKl[i] = lo;
    return;
  }
  i -= M_*64;
  if (i < 4096) {          // w1: [64,18] -> [64,64] padded
    int n = i >> 6, k = i & 63;
    float v = (k < 18) ? w1[n*18 + k] : 0.f;
    split_bf16(v, hi, lo); w1h[i] = hi; w1l[i] = lo; return;
  }
  i -= 4096;
  if (i < 40960) { split_bf16(w2[i],  hi, lo); w2h[i]=hi;  w2l[i]=lo;  return; }
  i -= 40960;
  if (i < 65536) { split_bf16(fw1[i], hi, lo); fw1h[i]=hi; fw1l[i]=lo; return; }
  i -= 65536;
  if (i < 131072){ split_bf16(fw2[i], hi, lo); fw2h[i]=hi; fw2l[i]=lo; return; }
}

// ---------------------------------------------------------------------------
// k_cheby1: one recurrence step (3 features): xn = alpha*(L@xc) - beta*xp.
// 2048 blocks x 256 (8 rows/block, 2 rows/wave) -> high occupancy for
// latency hiding.  x of this batch staged in LDS transposed (24 KB).
// ---------------------------------------------------------------------------
__global__ __launch_bounds__(256) void k_cheby1(const float* __restrict__ L,
    const float* __restrict__ xc, const float* __restrict__ xp,
    float* __restrict__ xn, short* __restrict__ XKh, short* __restrict__ XKl,
    float alpha, float beta, int kidx) {
  __shared__ float sx[3][V_];  // 24 KB
  int b  = blockIdx.x >> 8;
  int r0 = (blockIdx.x & 255) * 8;
  const float* xcb = xc + (size_t)b*V_*D_;
  for (int i = threadIdx.x; i < V_*D_; i += 256) {
    int u = i / 3, f = i - u*3;
    sx[f][u] = xcb[i];
  }
  __syncthreads();
  int w = threadIdx.x >> 6, lane = threadIdx.x & 63;
  const float4* X0 = (const float4*)sx[0];
  const float4* X1 = (const float4*)sx[1];
  const float4* X2 = (const float4*)sx[2];
  int rA = r0 + w*2;
  int rB = rA + 1;
  const float4* LA = (const float4*)(L + ((size_t)b*V_ + rA)*V_);
  const float4* LB = (const float4*)(L + ((size_t)b*V_ + rB)*V_);
  float a0=0.f,a1=0.f,a2=0.f,b0=0.f,b1=0.f,b2=0.f;
  #pragma unroll
  for (int it = 0; it < 8; it++) {
    int u4 = it*64 + lane;
    float4 la = LA[u4], lb = LB[u4];
    float4 x0 = X0[u4], x1 = X1[u4], x2 = X2[u4];
    a0 = fmaf(la.x,x0.x,fmaf(la.y,x0.y,fmaf(la.z,x0.z,fmaf(la.w,x0.w,a0))));
    a1 = fmaf(la.x,x1.x,fmaf(la.y,x1.y,fmaf(la.z,x1.z,fmaf(la.w,x1.w,a1))));
    a2 = fmaf(la.x,x2.x,fmaf(la.y,x2.y,fmaf(la.z,x2.z,fmaf(la.w,x2.w,a2))));
    b0 = fmaf(lb.x,x0.x,fmaf(lb.y,x0.y,fmaf(lb.z,x0.z,fmaf(lb.w,x0.w,b0))));
    b1 = fmaf(lb.x,x1.x,fmaf(lb.y,x1.y,fmaf(lb.z,x1.z,fmaf(lb.w,x1.w,b1))));
    b2 = fmaf(lb.x,x2.x,fmaf(lb.y,x2.y,fmaf(lb.z,x2.z,fmaf(lb.w,x2.w,b2))));
  }
  #pragma unroll
  for (int off = 32; off > 0; off >>= 1) {
    a0 += __shfl_down(a0, off); a1 += __shfl_down(a1, off);
    a2 += __shfl_down(a2, off); b0 += __shfl_down(b0, off);
    b1 += __shfl_down(b1, off); b2 += __shfl_down(b2, off);
  }
  if (lane == 0) {
    float vA[3] = {alpha*a0, alpha*a1, alpha*a2};
    float vB[3] = {alpha*b0, alpha*b1, alpha*b2};
    size_t baseA = ((size_t)b*V_ + rA)*3;
    size_t baseB = ((size_t)b*V_ + rB)*3;
    if (beta != 0.f) {
      #pragma unroll
      for (int f = 0; f < 3; f++) {
        vA[f] -= beta * xp[baseA + f];
        vB[f] -= beta * xp[baseB + f];
      }
    }
    #pragma unroll
    for (int f = 0; f < 3; f++) {
      xn[baseA + f] = vA[f];
      xn[baseB + f] = vB[f];
      short hi, lo;
      split_bf16(vA[f], hi, lo);
      size_t oA = ((size_t)b*V_ + rA)*64 + f*6 + kidx;
      XKh[oA] = hi; XKl[oA] = lo;
      split_bf16(vB[f], hi, lo);
      size_t oB = ((size_t)b*V_ + rB)*64 + f*6 + kidx;
      XKh[oB] = hi; XKl[oB] = lo;
    }
  }
}

// ---------------------------------------------------------------------------
// k_cheby2_mfma: Zn = alpha*(L @ z) - beta*Zp ; split-bf16 MFMA.
// 16-row x 64-col tiles -> 1024 blocks, LDS 20 KB -> 4 blocks/CU, 16 waves/CU.
// Wave w covers cols w*16..w*16+15 (16x16 MFMA per wave).
// Epilogue: Zn fp32 ping-pong, ZK pack (slot kidx), next-step hi/lo transposed.
// ---------------------------------------------------------------------------
__global__ __launch_bounds__(256) void k_cheby2_mfma(const float* __restrict__ L,
    const short* __restrict__ Zth, const short* __restrict__ Ztl,
    const float* __restrict__ Zp,
    float* __restrict__ Zn, short* __restrict__ ZKh, short* __restrict__ ZKl,
    short* __restrict__ Znth, short* __restrict__ Zntl,
    float alpha, float beta, int kidx) {
  __shared__ float sA[16*64];    // L tile  [r][k], chunk-swizzled, 4 KB
  __shared__ short sBh[64*64];   // Zt hi   [n][k], chunk-swizzled, 8 KB
  __shared__ short sBl[64*64];   // Zt lo   [n][k], chunk-swizzled, 8 KB

  int b  = blockIdx.x >> 7;
  int r0 = (blockIdx.x & 127) * 16;
  const float* Lb   = L   + (size_t)b*V_*V_;
  const short* Zthb = Zth + (size_t)b*64*V_;
  const short* Ztlb = Ztl + (size_t)b*64*V_;

  int tid  = threadIdx.x;
  int w    = tid >> 6;           // wave 0..3 -> col quarter
  int lane = tid & 63;
  int lm   = lane & 15;
  int quad = lane >> 4;
  int cbase = w * 16;

  const f32x4*  sAv  = (const f32x4*)sA;
  const short8* sBhv = (const short8*)sBh;
  const short8* sBlv = (const short8*)sBl;

  f32x4 acc = {0.f,0.f,0.f,0.f};

  for (int s = 0; s < V_/64; s++) {
    int k0 = s * 64;
    if (s) __syncthreads();
    // stage A: 16 rows x 64 floats = 4 KB = 256 threads x 16B
    {
      int f = tid;
      int r = f >> 4, cc = f & 15;
      int c = cc ^ r;              // r in 0..15
      async_copy16(Lb + (size_t)(r0 + r)*V_ + k0 + c*4, &sA[f*4]);
    }
    // stage B: 64 n x 64 k bf16 = 8 KB each -> 2 iters x 256 threads x 16B
    #pragma unroll
    for (int t = 0; t < 2; t++) {
      int f = t*256 + tid;
      int n = f >> 3, cc = f & 7;
      int c = cc ^ (n & 7);
      async_copy16(Zthb + (size_t)n*V_ + k0 + c*8, &sBh[f*8]);
      async_copy16(Ztlb + (size_t)n*V_ + k0 + c*8, &sBl[f*8]);
    }
    __syncthreads();

    #pragma unroll
    for (int ks = 0; ks < 2; ks++) {
      int koff = ks * 32;
      // A fragment: 8 fp32 -> hi/lo bf16 (row lm, k = koff + quad*8 + j)
      int r = lm;
      int c0 = (koff >> 2) + 2*quad;
      f32x4 a0 = sAv[r*16 + (c0 ^ r)];
      f32x4 a1 = sAv[r*16 + ((c0 + 1) ^ r)];
      float av[8] = {a0.x, a0.y, a0.z, a0.w, a1.x, a1.y, a1.z, a1.w};
      short8 ah, al;
      #pragma unroll
      for (int j = 0; j < 8; j++) {
        short hi, lo; split_bf16(av[j], hi, lo);
        ah[j] = hi; al[j] = lo;
      }
      int cb = (koff >> 3) + quad;
      int n = cbase + lm;
      short8 bh = sBhv[n*8 + (cb ^ (n & 7))];
      short8 bl = sBlv[n*8 + (cb ^ (n & 7))];
      acc = __builtin_amdgcn_mfma_f32_16x16x32_bf16(ah, bh, acc, 0, 0, 0);
      acc = __builtin_amdgcn_mfma_f32_16x16x32_bf16(ah, bl, acc, 0, 0, 0);
      acc = __builtin_amdgcn_mfma_f32_16x16x32_bf16(al, bh, acc, 0, 0, 0);
    }
  }

  // epilogue: C/D layout col=lane&15, row=quad*4+reg
  int n = cbase + lm;
  #pragma unroll
  for (int i = 0; i < 4; i++) {
    int r = r0 + quad*4 + i;
    size_t rowb = (size_t)b*V_ + r;
    float v = alpha * acc[i];
    if (beta != 0.f) v -= beta * Zp[rowb*64 + n];
    Zn[rowb*64 + n] = v;
    short hi, lo; split_bf16(v, hi, lo);
    size_t ok = rowb*320 + (size_t)n*5 + kidx;
    ZKh[ok] = hi; ZKl[ok] = lo;
    size_t o = ((size_t)b*64 + n)*V_ + r;
    Znth[o] = hi; Zntl[o] = lo;
  }
}

// ---------------------------------------------------------------------------
// gemm_tile: one 64x64 output tile of C = relu(A[M,K] @ W[N,K]^T + bias),
// split-bf16 MFMA.  A/W pre-split hi/lo bf16, K mult of 64.
// ---------------------------------------------------------------------------
__device__ __forceinline__ void gemm_tile(
    const short* __restrict__ Ah, const short* __restrict__ Al,
    const short* __restrict__ Wh, const short* __restrict__ Wl,
    const float* __restrict__ bias, int N, int K, int row0, int col0,
    short* sAh, short* sAl, short* sWh, short* sWl,
    float* __restrict__ Cf, short* __restrict__ Ch, short* __restrict__ Cl,
    short* __restrict__ Ph, short* __restrict__ Pl, int packMul, int packStride,
    short* __restrict__ Th, short* __restrict__ Tl) {
  int tid = threadIdx.x, w = tid >> 6, lane = tid & 63;
  int lm = lane & 15, quad = lane >> 4;
  int wm = (w & 1) * 32, wn = (w >> 1) * 32;

  const short8* vAh = (const short8*)sAh;
  const short8* vAl = (const short8*)sAl;
  const short8* vWh = (const short8*)sWh;
  const short8* vWl = (const short8*)sWl;

  f32x4 acc[2][2] = {{{0.f,0.f,0.f,0.f},{0.f,0.f,0.f,0.f}},
                     {{0.f,0.f,0.f,0.f},{0.f,0.f,0.f,0.f}}};

  for (int k0 = 0; k0 < K; k0 += 64) {
    if (k0) __syncthreads();
    #pragma unroll
    for (int t = 0; t < 2; t++) {
      int f = t*256 + tid;
      int r = f >> 3, p = f & 7;
      int c = p ^ (r & 7);
      size_t goA = (size_t)(row0 + r)*K + k0 + c*8;
      size_t goW = (size_t)(col0 + r)*K + k0 + c*8;
      async_copy16(Ah + goA, &sAh[f*8]);
      async_copy16(Al + goA, &sAl[f*8]);
      async_copy16(Wh + goW, &sWh[f*8]);
      async_copy16(Wl + goW, &sWl[f*8]);
    }
    __syncthreads();

    #pragma unroll
    for (int ks = 0; ks < 2; ks++) {
      int kc = ks*4 + quad;
      short8 a_h[2], a_l[2], b_h[2], b_l[2];
      #pragma unroll
      for (int i = 0; i < 2; i++) {
        int m = wm + i*16 + lm;
        a_h[i] = vAh[m*8 + (kc ^ (m & 7))];
        a_l[i] = vAl[m*8 + (kc ^ (m & 7))];
      }
      #pragma unroll
      for (int j = 0; j < 2; j++) {
        int n = wn + j*16 + lm;
        b_h[j] = vWh[n*8 + (kc ^ (n & 7))];
        b_l[j] = vWl[n*8 + (kc ^ (n & 7))];
      }
      #pragma unroll
      for (int i = 0; i < 2; i++)
        #pragma unroll
        for (int j = 0; j < 2; j++) {
          acc[i][j] = __builtin_amdgcn_mfma_f32_16x16x32_bf16(a_h[i], b_h[j], acc[i][j], 0, 0, 0);
          acc[i][j] = __builtin_amdgcn_mfma_f32_16x16x32_bf16(a_h[i], b_l[j], acc[i][j], 0, 0, 0);
          acc[i][j] = __builtin_amdgcn_mfma_f32_16x16x32_bf16(a_l[i], b_h[j], acc[i][j], 0, 0, 0);
        }
    }
  }

  #pragma unroll
  for (int i = 0; i < 2; i++)
    #pragma unroll
    for (int j = 0; j < 2; j++) {
      int col = col0 + wn + j*16 + lm;
      float bj = bias[col];
      #pragma unroll
      for (int g = 0; g < 4; g++) {
        int row = row0 + wm + i*16 + quad*4 + g;
        float v = acc[i][j][g] + bj;
        v = v > 0.f ? v : 0.f;
        if (Cf) Cf[(size_t)row*N + col] = v;
        short hi, lo;
        if (Ch || Ph || Th) split_bf16(v, hi, lo);
        if (Ch) {
          Ch[(size_t)row*N + col] = hi;
          Cl[(size_t)row*N + col] = lo;
        }
        if (Ph) {
          size_t o = (size_t)row*packStride + (size_t)col*packMul;
          Ph[o] = hi; Pl[o] = lo;
        }
        if (Th) {  // transposed [B,64,V] (N==64)
          int bb = row >> 11, vv = row & (V_-1);
          size_t o = ((size_t)bb*64 + col)*V_ + vv;
          Th[o] = hi; Tl[o] = lo;
        }
      }
    }
}

// ---------------------------------------------------------------------------
// k_gemm_y1: y1 = relu(XK @ w1^T + b1); writes y1 fp32, ZK pack slot 0,
// and ZtA hi/lo transposed.  256 blocks (N=64).
// ---------------------------------------------------------------------------
__global__ __launch_bounds__(256) void k_gemm_y1(
    const short* __restrict__ XKh, const short* __restrict__ XKl,
    const short* __restrict__ w1h, const short* __restrict__ w1l,
    const float* __restrict__ b1, float* __restrict__ y1,
    short* __restrict__ ZKh, short* __restrict__ ZKl,
    short* __restrict__ Th, short* __restrict__ Tl) {
  __shared__ short sAh[64*64], sAl[64*64], sWh[64*64], sWl[64*64];
  gemm_tile(XKh, XKl, w1h, w1l, b1, 64, 64, blockIdx.x*64, 0,
            sAh, sAl, sWh, sWl,
            y1, nullptr, nullptr, ZKh, ZKl, 5, 320, Th, Tl);
}

// ---------------------------------------------------------------------------
// k_gemm_bf16: generic FC GEMM, 64x64 tiles.
// ---------------------------------------------------------------------------
__global__ __launch_bounds__(256) void k_gemm_bf16(
    const short* __restrict__ Ah, const short* __restrict__ Al,
    const short* __restrict__ Wh, const short* __restrict__ Wl,
    const float* __restrict__ bias, int N, int K,
    float* __restrict__ Cf, short* __restrict__ Ch, short* __restrict__ Cl) {
  __shared__ short sAh[64*64], sAl[64*64], sWh[64*64], sWl[64*64];
  int bm = blockIdx.x & 255;       // M_/64 = 256
  int bn = blockIdx.x >> 8;
  gemm_tile(Ah, Al, Wh, Wl, bias, N, K, bm*64, bn*64,
            sAh, sAl, sWh, sWl,
            Cf, Ch, Cl, nullptr, nullptr, 0, 0, nullptr, nullptr);
}

// ---------------------------------------------------------------------------
extern "C" void kernel_launch(void* const* d_in, const int* in_sizes, int n_in,
                              void* d_out, int out_size, void* d_ws, size_t ws_size,
                              hipStream_t stream) {
  const float* x   = (const float*)d_in[0];
  const float* L   = (const float*)d_in[1];
  const float* w1  = (const float*)d_in[2];
  const float* b1  = (const float*)d_in[3];
  const float* w2  = (const float*)d_in[4];
  const float* b2  = (const float*)d_in[5];
  const float* fw1 = (const float*)d_in[6];
  const float* fb1 = (const float*)d_in[7];
  const float* fw2 = (const float*)d_in[8];
  const float* fb2 = (const float*)d_in[9];
  float* out = (float*)d_out;

  float* p  = (float*)d_ws;
  float* xa = p;  p += (size_t)B_*V_*D_;
  float* xb = p;  p += (size_t)B_*V_*D_;
  float* xc = p;  p += (size_t)B_*V_*D_;
  float* y1 = p;  p += (size_t)M_*64;
  float* zb = p;  p += (size_t)M_*64;
  float* zc = p;  p += (size_t)M_*64;
  short* sp = (short*)p;
  short* ZKh = sp;  sp += (size_t)M_*320;
  short* ZKl = sp;  sp += (size_t)M_*320;
  short* y2h = sp;  sp += (size_t)M_*128;
  short* y2l = sp;  sp += (size_t)M_*128;
  short* h1h = sp;  sp += (size_t)M_*512;
  short* h1l = sp;  sp += (size_t)M_*512;
  short* ZtAh = sp; sp += (size_t)M_*64;
  short* ZtAl = sp; sp += (size_t)M_*64;
  short* ZtBh = sp; sp += (size_t)M_*64;
  short* ZtBl = sp; sp += (size_t)M_*64;
  short* w1h = sp;  sp += 64*64;
  short* w1l = sp;  sp += 64*64;
  short* w2h = sp;  sp += 128*320;
  short* w2l = sp;  sp += 128*320;
  short* fw1h = sp; sp += 512*128;
  short* fw1l = sp; sp += 512*128;
  short* fw2h = sp; sp += 256*512;
  short* fw2l = sp; sp += 256*512;
  // XK aliased into h1h region (disjoint lifetimes: XK dead before h1 written)
  short* XKh = h1h;
  short* XKl = h1h + (size_t)M_*64;

  // 1) prep: XK (slot0 + zero pads) + xa transpose + weight splits
  k_prep<<<5040, 256, 0, stream>>>(x, w1, w2, fw1, fw2, xa,
                                   XKh, XKl, w1h, w1l, w2h, w2l,
                                   fw1h, fw1l, fw2h, fw2l);

  // 2) cheby1: x0=xa, x1=xb, x2=xc, x3=xa, x4=xb, x5=xc  (2048 blocks each)
  k_cheby1<<<2048, 256, 0, stream>>>(L, xa, xa, xb, XKh, XKl, 1.f, 0.f, 1);
  k_cheby1<<<2048, 256, 0, stream>>>(L, xb, xa, xc, XKh, XKl, 2.f, 1.f, 2);
  k_cheby1<<<2048, 256, 0, stream>>>(L, xc, xb, xa, XKh, XKl, 2.f, 1.f, 3);
  k_cheby1<<<2048, 256, 0, stream>>>(L, xa, xc, xb, XKh, XKl, 2.f, 1.f, 4);
  k_cheby1<<<2048, 256, 0, stream>>>(L, xb, xa, xc, XKh, XKl, 2.f, 1.f, 5);

  // 3) y1-GEMM (+ ZK slot 0 pack + ZtA transposed split)
  k_gemm_y1<<<256, 256, 0, stream>>>(XKh, XKl, w1h, w1l, b1,
                                     y1, ZKh, ZKl, ZtAh, ZtAl);

  // 4) cheby2 (MFMA, 1024 blocks each): z1=zb, z2=zc, z3->y1, z4->zb
  k_cheby2_mfma<<<1024, 256, 0, stream>>>(L, ZtAh, ZtAl, y1, zb, ZKh, ZKl,
                                          ZtBh, ZtBl, 1.f, 0.f, 1);
  k_cheby2_mfma<<<1024, 256, 0, stream>>>(L, ZtBh, ZtBl, y1, zc, ZKh, ZKl,
                                          ZtAh, ZtAl, 2.f, 1.f, 2);
  k_cheby2_mfma<<<1024, 256, 0, stream>>>(L, ZtAh, ZtAl, zb, y1, ZKh, ZKl,
                                          ZtBh, ZtBl, 2.f, 1.f, 3);
  k_cheby2_mfma<<<1024, 256, 0, stream>>>(L, ZtBh, ZtBl, zc, zb, ZKh, ZKl,
                                          ZtAh, ZtAl, 2.f, 1.f, 4);

  // 5) FC chain
  k_gemm_bf16<<<512, 256, 0, stream>>>(ZKh, ZKl, w2h, w2l, b2, 128, 320,
                                       nullptr, y2h, y2l);
  k_gemm_bf16<<<2048, 256, 0, stream>>>(y2h, y2l, fw1h, fw1l, fb1, 512, 128,
                                        nullptr, h1h, h1l);
  k_gemm_bf16<<<1024, 256, 0, stream>>>(h1h, h1l, fw2h, fw2l, fb2, 256, 512,
                                        out, nullptr, nullptr);
}